// Round 15
// baseline (236.463 us; speedup 1.0000x reference)
//
#include <hip/hip_runtime.h>
#include <math.h>

// ================= problem constants =================
#define B_SZ   4096
#define UNITS  2048
#define N_IN   1024
#define N_OUT  1024
#define N_LIF  1024

#define DECAY_C   0.951229424500714f     // exp(-1/20)
#define KAPPA_C   0.951229424500714f     // exp(-1/20)
#define DECAYB_C  0.9983347214509387f    // exp(-1/600)
#define THR_C     0.4f
#define BETA_C    1.6f
#define NREF_C    5.0f
#define TAU_C     3e-3f                  // fixup band (~7.5 sigma of fp16 GEMM noise)
#define FIX_CAP   131072
#define NFIXWAVES 2048

typedef _Float16 half8 __attribute__((ext_vector_type(8)));
typedef float  f32x4  __attribute__((ext_vector_type(4)));
typedef unsigned short ushort_t;
typedef unsigned short us8 __attribute__((ext_vector_type(8)));
typedef __bf16 bf16x8 __attribute__((ext_vector_type(8)));

// ---------- conversion helpers ----------
__device__ __forceinline__ unsigned short f2bf(float f) {   // RNE bf16
    unsigned int u = __float_as_uint(f);
    unsigned int r = (u + 0x7fffu + ((u >> 16) & 1u)) >> 16;
    return (unsigned short)r;
}
__device__ __forceinline__ unsigned short f2h(float f) {    // RNE fp16
    _Float16 h = (_Float16)f;
    return __builtin_bit_cast(unsigned short, h);
}

__device__ __forceinline__ void gload_lds16(const ushort_t* g, ushort_t* l) {
    __builtin_amdgcn_global_load_lds(
        (const __attribute__((address_space(1))) unsigned int*)g,
        (__attribute__((address_space(3))) unsigned int*)l, 16, 0, 0);
}

__device__ __forceinline__ double shflxor_d(double x, int m) {
    long long vl = __double_as_longlong(x);
    int lo = (int)(vl & 0xffffffffLL), hi = (int)(vl >> 32);
    lo = __shfl_xor(lo, m, 64);
    hi = __shfl_xor(hi, m, 64);
    return __longlong_as_double(((long long)hi << 32) | (unsigned int)(unsigned)lo);
}

// ================= fused prep (all conversions in one kernel) ==============
// Panel per (blk, kpanel): [c:8][row:128][e:8] = 8192 elems = 16KB.

__device__ __forceinline__ void tileA16_body(const float* __restrict__ src, int K,
                                             ushort_t* __restrict__ dst,
                                             int rb, int kp, int tid) {
    const int KP = K >> 6;
    size_t base = ((size_t)rb * KP + kp) * 8192;
#pragma unroll
    for (int it = 0; it < 4; ++it) {
        int unit = it * 256 + tid;
        int c = unit >> 7, row = unit & 127;
        const float* s = src + (size_t)(rb * 128 + row) * K + kp * 64 + c * 8;
        float4 a  = *reinterpret_cast<const float4*>(s);
        float4 b4 = *reinterpret_cast<const float4*>(s + 4);
        float vals[8] = {a.x, a.y, a.z, a.w, b4.x, b4.y, b4.z, b4.w};
        us8 h;
#pragma unroll
        for (int e = 0; e < 8; ++e) h[e] = f2h(vals[e]);
        *reinterpret_cast<us8*>(dst + base + (size_t)c * 1024 + row * 8) = h;
    }
}

__device__ __forceinline__ void tileW16_body(const float* __restrict__ src, int N, int K,
                                             ushort_t* __restrict__ dst,
                                             int cb, int kp, int tid) {
    const int KP = K >> 6;
    size_t base = ((size_t)cb * KP + kp) * 8192;
#pragma unroll
    for (int it = 0; it < 4; ++it) {
        int unit = it * 256 + tid;
        int c = unit >> 7, n = unit & 127;
        const float* s = src + (size_t)(kp * 64 + c * 8) * N + cb * 128 + n;
        us8 h;
#pragma unroll
        for (int e = 0; e < 8; ++e) h[e] = f2h(s[(size_t)e * N]);
        *reinterpret_cast<us8*>(dst + base + (size_t)c * 1024 + n * 8) = h;
    }
}

__device__ __forceinline__ void tileWbf_body(const float* __restrict__ src, int N, int K,
                                             ushort_t* __restrict__ dst,
                                             int cb, int kp, int tid) {
    const int KP = K >> 6;
    size_t base = ((size_t)cb * KP + kp) * 8192;
#pragma unroll
    for (int it = 0; it < 4; ++it) {
        int unit = it * 256 + tid;
        int c = unit >> 7, n = unit & 127;
        const float* s = src + (size_t)(kp * 64 + c * 8) * N + cb * 128 + n;
        us8 h;
#pragma unroll
        for (int e = 0; e < 8; ++e) h[e] = f2bf(s[(size_t)e * N]);
        *reinterpret_cast<us8*>(dst + base + (size_t)c * 1024 + n * 8) = h;
    }
}

__global__ __launch_bounds__(256)
void prep_all(const float* __restrict__ x, const float* __restrict__ z,
              const float* __restrict__ w_in, const float* __restrict__ w_rec,
              const float* __restrict__ w_out,
              ushort_t* __restrict__ xhT, ushort_t* __restrict__ zbT,
              ushort_t* __restrict__ wiT, ushort_t* __restrict__ wrT,
              ushort_t* __restrict__ woHT, float* __restrict__ wiT32,
              unsigned* __restrict__ cnt) {
    __shared__ float tile[64][65];
    const int bid = blockIdx.x, tid = threadIdx.x;
    if (bid == 0 && tid == 0) *cnt = 0;

    if (bid < 512) {                       // x -> fp16 tiles (32 x 16)
        tileA16_body(x, N_IN, xhT, bid & 31, bid >> 5, tid);
    } else if (bid < 1536) {               // z -> fp16 tiles (32 x 32)
        int u = bid - 512;
        tileA16_body(z, UNITS, zbT, u & 31, u >> 5, tid);
    } else if (bid < 1792) {               // w_in -> fp16 W^T (16 x 16)
        int u = bid - 1536;
        tileW16_body(w_in, UNITS, N_IN, wiT, u & 15, u >> 4, tid);
    } else if (bid < 2304) {               // w_rec -> fp16 W^T (16 x 32)
        int u = bid - 1792;
        tileW16_body(w_rec, UNITS, UNITS, wrT, u & 15, u >> 4, tid);
    } else if (bid < 2560) {               // w_out -> bf16 W^T (8 x 32)
        int u = bid - 2304;
        tileWbf_body(w_out, N_OUT, UNITS, woHT, u & 7, u >> 3, tid);
    } else {                               // w_in fp32 transpose (32 x 16)
        int u = bid - 2560;
        const int n0 = (u & 31) * 64, k0 = (u >> 5) * 64;
        const int tr = tid >> 4, tc = tid & 15;
#pragma unroll
        for (int i = 0; i < 4; ++i) {
            int rr = tr + i * 16;
            float4 v = *reinterpret_cast<const float4*>(
                &w_in[(size_t)(k0 + rr) * UNITS + n0 + tc * 4]);
            tile[rr][tc * 4 + 0] = v.x; tile[rr][tc * 4 + 1] = v.y;
            tile[rr][tc * 4 + 2] = v.z; tile[rr][tc * 4 + 3] = v.w;
        }
        __syncthreads();
#pragma unroll
        for (int i = 0; i < 4; ++i) {
            int nl = tr + i * 16;
            float4 o;
            o.x = tile[tc * 4 + 0][nl]; o.y = tile[tc * 4 + 1][nl];
            o.z = tile[tc * 4 + 2][nl]; o.w = tile[tc * 4 + 3][nl];
            *reinterpret_cast<float4*>(&wiT32[(size_t)(n0 + nl) * N_IN + k0 + tc * 4]) = o;
        }
    }
}

// ====== MFMA GEMM1 fp16 (48 steps: x16*wi16 + z16*wr16), 8x8 XCD tiles =====
__device__ __forceinline__ void resolve1(
    int t, int rby, int cbx,
    const ushort_t* xhT, const ushort_t* zbT,
    const ushort_t* wiT, const ushort_t* wrT,
    const ushort_t*& a, const ushort_t*& bb) {
    if (t < 16) { a = xhT + ((size_t)rby * 16 + t) * 8192;
                  bb = wiT + ((size_t)cbx * 16 + t) * 8192; }
    else        { a = zbT + ((size_t)rby * 32 + t - 16) * 8192;
                  bb = wrT + ((size_t)cbx * 32 + t - 16) * 8192; }
}

__global__ __launch_bounds__(256)
void mfma_gemm1(const ushort_t* __restrict__ xhT, const ushort_t* __restrict__ zbT,
                const ushort_t* __restrict__ wiT, const ushort_t* __restrict__ wrT,
                const float* __restrict__ v,
                const float* __restrict__ r, const float* __restrict__ b,
                float* __restrict__ oz, float* __restrict__ ov,
                float* __restrict__ orr, float* __restrict__ ob,
                ushort_t* __restrict__ nzbT,
                unsigned* __restrict__ cnt, unsigned* __restrict__ list) {
    __shared__ ushort_t As[2][8192];
    __shared__ ushort_t Bs[2][8192];
    const int t = threadIdx.x, lane = t & 63, w = t >> 6;
    const int wm = w >> 1, wn = w & 1;
    // 8x8 per-XCD super-tiles: XCD x owns rby in [ (x>>1)*8, +8 ), cbx in [ (x&1)*8, +8 )
    const int bid = blockIdx.x;
    const int xcd = bid & 7, ii = bid >> 3;
    const int rby = (xcd >> 1) * 8 + (ii >> 3);
    const int cbx = (xcd & 1) * 8 + (ii & 7);
    const int row0 = rby * 128, col0 = cbx * 128;
    const int l4 = lane >> 4, l15 = lane & 15;

    f32x4 acc[4][4];
#pragma unroll
    for (int m = 0; m < 4; ++m)
#pragma unroll
        for (int n = 0; n < 4; ++n)
#pragma unroll
            for (int i = 0; i < 4; ++i) acc[m][n][i] = 0.f;

    auto stage = [&](const ushort_t* aB, const ushort_t* bB, int buf) {
#pragma unroll
        for (int c = 0; c < 4; ++c) {
            int ch = w * 4 + c;                   // 16 chunks of 1KB
            gload_lds16(aB + ch * 512 + lane * 8, &As[buf][ch * 512]);
            gload_lds16(bB + ch * 512 + lane * 8, &Bs[buf][ch * 512]);
        }
    };

    {   // prologue
        const ushort_t *a, *bb;
        resolve1(0, rby, cbx, xhT, zbT, wiT, wrT, a, bb);
        stage(a, bb, 0);
    }
    __syncthreads();

    int cur = 0;
    for (int step = 0; step < 48; ++step) {
        if (step + 1 < 48) {
            const ushort_t *a, *bb;
            resolve1(step + 1, rby, cbx, xhT, zbT, wiT, wrT, a, bb);
            stage(a, bb, cur ^ 1);
        }
        const ushort_t* Ab = As[cur];
        const ushort_t* Bb = Bs[cur];
#pragma unroll
        for (int kk = 0; kk < 2; ++kk) {
            half8 af[4], bfr[4];
            const int cBase = (kk * 4 + l4) * 1024;     // [c][row][8] layout
#pragma unroll
            for (int m = 0; m < 4; ++m)
                af[m] = *reinterpret_cast<const half8*>(Ab + cBase + (wm * 64 + m * 16 + l15) * 8);
#pragma unroll
            for (int n = 0; n < 4; ++n)
                bfr[n] = *reinterpret_cast<const half8*>(Bb + cBase + (wn * 64 + n * 16 + l15) * 8);
#pragma unroll
            for (int m = 0; m < 4; ++m)
#pragma unroll
                for (int n = 0; n < 4; ++n)
                    acc[m][n] = __builtin_amdgcn_mfma_f32_16x16x32_f16(
                        af[m], bfr[n], acc[m][n], 0, 0, 0);
        }
        __syncthreads();
        cur ^= 1;
    }
    // K-loop done; final barrier above means no wave still reads As/Bs.
    // Reuse As (32KB) as the block's bf16 new_z tile [128 rows][128 cols].
    ushort_t* ztile = &As[0][0];

    // ---- fused LSNN state-update epilogue (wave-aggregated candidate alloc) ----
    // zv read from zbT (fp16, bit-exact for {0,1}) — halves z-traffic vs fp32.
    unsigned long long pack = 0ull;
    int ncand = 0;
#pragma unroll
    for (int m = 0; m < 4; ++m)
#pragma unroll
        for (int i = 0; i < 4; ++i) {
            int grow = row0 + wm * 64 + m * 16 + l4 * 4 + i;
            size_t rbase = (size_t)grow * UNITS;
            size_t zrowb = ((size_t)(grow >> 7) * 32) * 8192 + (grow & 127) * 8;
#pragma unroll
            for (int n = 0; n < 4; ++n) {
                int gcol = col0 + wn * 64 + n * 16 + l15;
                size_t idx = rbase + gcol;
                int kp2 = gcol >> 6, c2 = (gcol & 63) >> 3, e2 = gcol & 7;
                float zv = (float)__builtin_bit_cast(
                    _Float16, zbT[zrowb + (size_t)kp2 * 8192 + c2 * 1024 + e2]);
                float it = acc[m][n][i];
                float bv = b[idx], vv = v[idx], rv = r[idx];
                float beta = (gcol < N_LIF) ? 0.f : BETA_C;
                float nb = DECAYB_C * bv + zv;
                float thr = THR_C + nb * beta;
                float nv = DECAY_C * vv + it - zv * THR_C;
                if (rv <= 0.f && fabsf(nv - thr) < TAU_C) {
                    int code = (m << 4) | (i << 2) | n;
                    if (ncand < 10) {
                        pack |= (unsigned long long)code << (6 * ncand);
                        ++ncand;
                    } else {            // overflow fallback (P ~ 0)
                        unsigned slot = atomicAdd(cnt, 1u);
                        if (slot < FIX_CAP)
                            list[slot] = ((unsigned)grow << 11) | (unsigned)gcol;
                    }
                }
                float nz = (rv > 0.f) ? 0.f : ((nv - thr > 0.f) ? 1.f : 0.f);
                float nr = fminf(fmaxf(rv + NREF_C * nz - 1.f, 0.f), NREF_C);
                oz[idx] = nz; ov[idx] = nv; orr[idx] = nr; ob[idx] = nb;
                ztile[(grow & 127) * 128 + (gcol & 127)]
                    = (nz > 0.f) ? (unsigned short)0x3F80 : (unsigned short)0;  // bf16 1.0
            }
        }

    unsigned scan = (unsigned)ncand;
#pragma unroll
    for (int off = 1; off < 64; off <<= 1) {
        unsigned up = (unsigned)__shfl_up((int)scan, off, 64);
        if (lane >= off) scan += up;
    }
    unsigned total = (unsigned)__shfl((int)scan, 63, 64);
    if (total > 0) {
        unsigned basev = 0;
        if (lane == 63) basev = atomicAdd(cnt, total);
        basev = (unsigned)__shfl((int)basev, 63, 64);
        unsigned myoff = basev + scan - (unsigned)ncand;
        for (int j = 0; j < ncand; ++j) {
            int code = (int)((pack >> (6 * j)) & 63ull);
            int m = code >> 4, i = (code >> 2) & 3, n = code & 3;
            int grow = row0 + wm * 64 + m * 16 + l4 * 4 + i;
            int gcol = col0 + wn * 64 + n * 16 + l15;
            unsigned slot = myoff + (unsigned)j;
            if (slot < FIX_CAP)
                list[slot] = ((unsigned)grow << 11) | (unsigned)gcol;
        }
    }

    // ---- cooperative coalesced writeout of the two 16KB nzbT panels ----
    // Region = panels kp = cbx*2, cbx*2+1 (contiguous). Linear index d:
    //   d = (kp&1)*8192 + c2*1024 + row*8 + e2  <=>  ztile[row*128 + (gcol&127)]
    __syncthreads();
    {
        ushort_t* dst = nzbT + ((size_t)rby * 32 + cbx * 2) * 8192;
        int d0 = t * 64;
#pragma unroll
        for (int j = 0; j < 8; ++j) {
            int d = d0 + j * 8;
            int p = d >> 13, c2 = (d >> 10) & 7, row = (d >> 3) & 127;
            us8 vsrc = *reinterpret_cast<const us8*>(&ztile[row * 128 + p * 64 + c2 * 8]);
            *reinterpret_cast<us8*>(&dst[d]) = vsrc;
        }
    }
}

// ================= deferred exact fixup (one wave per candidate, fp64) ======
__global__ __launch_bounds__(256)
void fixup_kernel(const float* __restrict__ x, const float* __restrict__ z,
                  const float* __restrict__ wiT32, const float* __restrict__ wr,
                  const float* __restrict__ v, const float* __restrict__ r,
                  const float* __restrict__ b,
                  float* __restrict__ oz, float* __restrict__ ov,
                  float* __restrict__ orr, ushort_t* __restrict__ nzbT,
                  const unsigned* __restrict__ cnt, const unsigned* __restrict__ list) {
    unsigned total = *cnt;
    if (total > FIX_CAP) total = FIX_CAP;
    const int lane = threadIdx.x & 63;
    const int wid = blockIdx.x * 4 + (threadIdx.x >> 6);
    for (unsigned ci = wid; ci < total; ci += NFIXWAVES) {
        unsigned enc = list[ci];
        int grow = (int)(enc >> 11), gcol = (int)(enc & 2047);
        const float* xr = x + (size_t)grow * N_IN;
        const float* zr = z + (size_t)grow * UNITS;
        const float* wc = wiT32 + (size_t)gcol * N_IN;
        double acc = 0.0;
#pragma unroll 8
        for (int j = 0; j < 16; ++j) {
            int k = lane + j * 64;
            acc = fma((double)xr[k], (double)wc[k], acc);
        }
#pragma unroll 4
        for (int j = 0; j < 32; ++j) {
            int k = lane + j * 64;
            float zk = zr[k];
            if (zk != 0.f)
                acc = fma((double)zk, (double)wr[(size_t)k * UNITS + gcol], acc);
        }
#pragma unroll
        for (int off = 32; off >= 1; off >>= 1) acc += shflxor_d(acc, off);
        if (lane == 0) {
            size_t idx = (size_t)grow * UNITS + gcol;
            float zv = z[idx], bv = b[idx], vv = v[idx], rv = r[idx];
            float beta = (gcol < N_LIF) ? 0.f : BETA_C;
            float nb = DECAYB_C * bv + zv;
            float thr = THR_C + nb * beta;
            double nvd = (double)DECAY_C * (double)vv + acc - (double)zv * (double)THR_C;
            float nz = (rv > 0.f) ? 0.f : ((nvd - (double)thr > 0.0) ? 1.f : 0.f);
            float nr = fminf(fmaxf(rv + NREF_C * nz - 1.f, 0.f), NREF_C);
            oz[idx] = nz; ov[idx] = (float)nvd; orr[idx] = nr;
            int kp2 = gcol >> 6, c2 = (gcol & 63) >> 3, e2 = gcol & 7;
            nzbT[((size_t)(grow >> 7) * 32 + kp2) * 8192 + c2 * 1024 + (grow & 127) * 8 + e2]
                = (nz > 0.f) ? (unsigned short)0x3F80 : (unsigned short)0;
        }
    }
}

// ====== MFMA GEMM2 bf16, split-K-in-block (2 wave-groups x 16 steps) ======
__global__ __launch_bounds__(512)
void mfma_gemm2(const ushort_t* __restrict__ nzbT, const ushort_t* __restrict__ woHT,
                const float* __restrict__ prev, float* __restrict__ nout) {
    __shared__ ushort_t As[2][2][8192];     // [grp][buf]
    __shared__ ushort_t Bs[2][2][8192];
    const int t = threadIdx.x, lane = t & 63, w8 = t >> 6;
    const int grp = w8 >> 2, w = w8 & 3;
    const int wm = w >> 1, wn = w & 1;
    const int bid = blockIdx.x;
    const int swz = (bid & 7) * 32 + (bid >> 3);   // 256 blocks, bijective
    const int rby = swz >> 3, cbx = swz & 7;
    const int row0 = rby * 128, col0 = cbx * 128;
    const int l4 = lane >> 4, l15 = lane & 15;

    f32x4 acc[4][4];
#pragma unroll
    for (int m = 0; m < 4; ++m)
#pragma unroll
        for (int n = 0; n < 4; ++n)
#pragma unroll
            for (int i = 0; i < 4; ++i) acc[m][n][i] = 0.f;

    auto stage = [&](int sc, int buf) {
        const ushort_t* aB = nzbT + ((size_t)rby * 32 + sc) * 8192;
        const ushort_t* bB = woHT + ((size_t)cbx * 32 + sc) * 8192;
#pragma unroll
        for (int c = 0; c < 4; ++c) {
            int ch = w * 4 + c;
            gload_lds16(aB + ch * 512 + lane * 8, &As[grp][buf][ch * 512]);
            gload_lds16(bB + ch * 512 + lane * 8, &Bs[grp][buf][ch * 512]);
        }
    };

    stage(grp * 16, 0);
    __syncthreads();
    int cur = 0;
    for (int step = 0; step < 16; ++step) {
        if (step + 1 < 16) stage(grp * 16 + step + 1, cur ^ 1);
        const ushort_t* Ab = As[grp][cur];
        const ushort_t* Bb = Bs[grp][cur];
#pragma unroll
        for (int kk = 0; kk < 2; ++kk) {
            bf16x8 af[4], bfr[4];
            const int cBase = (kk * 4 + l4) * 1024;
#pragma unroll
            for (int m = 0; m < 4; ++m)
                af[m] = *reinterpret_cast<const bf16x8*>(Ab + cBase + (wm * 64 + m * 16 + l15) * 8);
#pragma unroll
            for (int n = 0; n < 4; ++n)
                bfr[n] = *reinterpret_cast<const bf16x8*>(Bb + cBase + (wn * 64 + n * 16 + l15) * 8);
#pragma unroll
            for (int m = 0; m < 4; ++m)
#pragma unroll
                for (int n = 0; n < 4; ++n)
                    acc[m][n] = __builtin_amdgcn_mfma_f32_16x16x32_bf16(
                        af[m], bfr[n], acc[m][n], 0, 0, 0);
        }
        __syncthreads();
        cur ^= 1;
    }

    // combine: group1 partials -> LDS (reuse As, 128*128 f32 = 64KB), group0 sums
    float* part = reinterpret_cast<float*>(As);
    if (grp == 1) {
#pragma unroll
        for (int m = 0; m < 4; ++m)
#pragma unroll
            for (int i = 0; i < 4; ++i) {
                int lr = wm * 64 + m * 16 + l4 * 4 + i;
#pragma unroll
                for (int n = 0; n < 4; ++n)
                    part[lr * 128 + wn * 64 + n * 16 + l15] = acc[m][n][i];
            }
    }
    __syncthreads();
    if (grp == 0) {
#pragma unroll
        for (int m = 0; m < 4; ++m)
#pragma unroll
            for (int i = 0; i < 4; ++i) {
                int lr = wm * 64 + m * 16 + l4 * 4 + i;
                size_t rbase = (size_t)(row0 + lr) * N_OUT;
#pragma unroll
                for (int n = 0; n < 4; ++n) {
                    int lc = wn * 64 + n * 16 + l15;
                    size_t idx = rbase + col0 + lc;
                    nout[idx] = KAPPA_C * prev[idx] + acc[m][n][i] + part[lr * 128 + lc];
                }
            }
    }
}

// ================= fp32 fallback (round-1 kernel; used if ws too small) =====
#define BM 128
#define BN 128
#define BK 16
#define TM 8
#define TN 8

__global__ __launch_bounds__(256)
void lsnn_gemm1(const float* __restrict__ x, const float* __restrict__ z,
                const float* __restrict__ w_in, const float* __restrict__ w_rec,
                const float* __restrict__ v, const float* __restrict__ r,
                const float* __restrict__ b,
                float* __restrict__ out_z, float* __restrict__ out_v,
                float* __restrict__ out_r, float* __restrict__ out_b) {
    __shared__ float As_[BK][BM + 4];
    __shared__ float Bs_[BK][BN + 4];
    const int bx = blockIdx.x, by = blockIdx.y, t = threadIdx.x;
    const int tx = t & 15, ty = t >> 4;
    const int row0 = by * BM, col0 = bx * BN;
    float acc[TM][TN];
#pragma unroll
    for (int i = 0; i < TM; ++i)
#pragma unroll
        for (int j = 0; j < TN; ++j) acc[i][j] = 0.f;
    for (int k0 = 0; k0 < N_IN + UNITS; k0 += BK) {
#pragma unroll
        for (int l = 0; l < 2; ++l) {
            int e = t + l * 256, arow = e >> 2, acol = (e & 3) * 4, gk = k0 + acol;
            const float* src = (gk < N_IN) ? (x + (size_t)(row0 + arow) * N_IN + gk)
                                           : (z + (size_t)(row0 + arow) * UNITS + (gk - N_IN));
            float4 av = *reinterpret_cast<const float4*>(src);
            As_[acol + 0][arow] = av.x; As_[acol + 1][arow] = av.y;
            As_[acol + 2][arow] = av.z; As_[acol + 3][arow] = av.w;
        }
#pragma unroll
        for (int l = 0; l < 2; ++l) {
            int e = t + l * 256, brow = e >> 5, bcol = (e & 31) * 4, gk = k0 + brow;
            const float* src = (gk < N_IN) ? (w_in + (size_t)gk * UNITS + col0 + bcol)
                                           : (w_rec + (size_t)(gk - N_IN) * UNITS + col0 + bcol);
            *reinterpret_cast<float4*>(&Bs_[brow][bcol]) = *reinterpret_cast<const float4*>(src);
        }
        __syncthreads();
#pragma unroll
        for (int kk = 0; kk < BK; ++kk) {
            float ra[TM], rb[TN];
#pragma unroll
            for (int i = 0; i < TM; ++i) ra[i] = As_[kk][ty * TM + i];
#pragma unroll
            for (int j = 0; j < TN; ++j) rb[j] = Bs_[kk][tx * TN + j];
#pragma unroll
            for (int i = 0; i < TM; ++i)
#pragma unroll
                for (int j = 0; j < TN; ++j) acc[i][j] = fmaf(ra[i], rb[j], acc[i][j]);
        }
        __syncthreads();
    }
#pragma unroll
    for (int i = 0; i < TM; ++i) {
        int gi = row0 + ty * TM + i;
        size_t base = (size_t)gi * UNITS;
#pragma unroll
        for (int j = 0; j < TN; ++j) {
            int gj = col0 + tx * TN + j;
            size_t idx = base + gj;
            float zv = z[idx], bv = b[idx], vv = v[idx], rv = r[idx];
            float beta = (gj < N_LIF) ? 0.f : BETA_C;
            float nb = DECAYB_C * bv + zv;
            float thr_ac = THR_C + nb * beta;
            float nv = DECAY_C * vv + acc[i][j] - zv * THR_C;
            float nz = (rv > 0.f) ? 0.f : (((nv - thr_ac) > 0.f) ? 1.f : 0.f);
            float nr = fminf(fmaxf(rv + NREF_C * nz - 1.f, 0.f), NREF_C);
            out_z[idx] = nz; out_v[idx] = nv; out_r[idx] = nr; out_b[idx] = nb;
        }
    }
}

__global__ __launch_bounds__(256)
void lsnn_gemm2(const float* __restrict__ nz, const float* __restrict__ w_out,
                const float* __restrict__ prev_out, float* __restrict__ new_out) {
    __shared__ float As_[BK][BM + 4];
    __shared__ float Bs_[BK][BN + 4];
    const int bx = blockIdx.x, by = blockIdx.y, t = threadIdx.x;
    const int tx = t & 15, ty = t >> 4;
    const int row0 = by * BM, col0 = bx * BN;
    float acc[TM][TN];
#pragma unroll
    for (int i = 0; i < TM; ++i)
#pragma unroll
        for (int j = 0; j < TN; ++j) acc[i][j] = 0.f;
    for (int k0 = 0; k0 < UNITS; k0 += BK) {
#pragma unroll
        for (int l = 0; l < 2; ++l) {
            int e = t + l * 256, arow = e >> 2, acol = (e & 3) * 4, gk = k0 + acol;
            float4 av = *reinterpret_cast<const float4*>(nz + (size_t)(row0 + arow) * UNITS + gk);
            As_[acol + 0][arow] = av.x; As_[acol + 1][arow] = av.y;
            As_[acol + 2][arow] = av.z; As_[acol + 3][arow] = av.w;
        }
#pragma unroll
        for (int l = 0; l < 2; ++l) {
            int e = t + l * 256, brow = e >> 5, bcol = (e & 31) * 4, gk = k0 + brow;
            *reinterpret_cast<float4*>(&Bs_[brow][bcol]) =
                *reinterpret_cast<const float4*>(w_out + (size_t)gk * N_OUT + col0 + bcol);
        }
        __syncthreads();
#pragma unroll
        for (int kk = 0; kk < BK; ++kk) {
            float ra[TM], rb[TN];
#pragma unroll
            for (int i = 0; i < TM; ++i) ra[i] = As_[kk][ty * TM + i];
#pragma unroll
            for (int j = 0; j < TN; ++j) rb[j] = Bs_[kk][tx * TN + j];
#pragma unroll
            for (int i = 0; i < TM; ++i)
#pragma unroll
                for (int j = 0; j < TN; ++j) acc[i][j] = fmaf(ra[i], rb[j], acc[i][j]);
        }
        __syncthreads();
    }
#pragma unroll
    for (int i = 0; i < TM; ++i) {
        int gi = row0 + ty * TM + i;
        size_t base = (size_t)gi * N_OUT;
#pragma unroll
        for (int j = 0; j < TN; ++j) {
            int gj = col0 + tx * TN + j;
            size_t idx = base + gj;
            new_out[idx] = KAPPA_C * prev_out[idx] + acc[i][j];
        }
    }
}

// ================= launch =================
extern "C" void kernel_launch(void* const* d_in, const int* in_sizes, int n_in,
                              void* d_out, int out_size, void* d_ws, size_t ws_size,
                              hipStream_t stream) {
    const float* x     = (const float*)d_in[0];
    const float* v     = (const float*)d_in[1];
    const float* z     = (const float*)d_in[2];
    const float* r     = (const float*)d_in[3];
    const float* out   = (const float*)d_in[4];
    const float* b     = (const float*)d_in[5];
    const float* w_in  = (const float*)d_in[6];
    const float* w_rec = (const float*)d_in[7];
    const float* w_out = (const float*)d_in[8];

    float* o       = (float*)d_out;
    float* new_out = o;
    float* new_z   = o + (size_t)B_SZ * N_OUT;
    float* new_v   = new_z + (size_t)B_SZ * UNITS;
    float* new_r   = new_v + (size_t)B_SZ * UNITS;
    float* new_b   = new_r + (size_t)B_SZ * UNITS;

    const size_t MB = 1u << 20;
    const size_t need = 66 * MB;
    if (ws_size >= need) {
        char* wsb = (char*)d_ws;
        ushort_t* xhT   = (ushort_t*)(wsb + 0 * MB);    // 8 MB  (fp16 x)
        ushort_t* zbT   = (ushort_t*)(wsb + 8 * MB);    // 16 MB (fp16 z, exact)
        ushort_t* nzbT  = (ushort_t*)(wsb + 24 * MB);   // 16 MB (bf16 new_z, tiled)
        ushort_t* wiT   = (ushort_t*)(wsb + 40 * MB);   // 4 MB  (fp16 w_in^T)
        ushort_t* wrT   = (ushort_t*)(wsb + 44 * MB);   // 8 MB  (fp16 w_rec^T)
        ushort_t* woHT  = (ushort_t*)(wsb + 52 * MB);   // 4 MB  (bf16 w_out^T)
        float*    wiT32 = (float*)   (wsb + 56 * MB);   // 8 MB  (fp32 w_in^T)
        unsigned* cnt   = (unsigned*)(wsb + 64 * MB);
        unsigned* list  = (unsigned*)(wsb + 64 * MB + 4096);  // 512 KB

        hipLaunchKernelGGL(prep_all, dim3(3072), dim3(256), 0, stream,
                           x, z, w_in, w_rec, w_out,
                           xhT, zbT, wiT, wrT, woHT, wiT32, cnt);
        hipLaunchKernelGGL(mfma_gemm1, dim3(512), dim3(256), 0, stream,
                           xhT, zbT, wiT, wrT,
                           v, r, b, new_z, new_v, new_r, new_b, nzbT, cnt, list);
        hipLaunchKernelGGL(fixup_kernel, dim3(NFIXWAVES / 4), dim3(256), 0, stream,
                           x, z, wiT32, w_rec, v, r, b, new_z, new_v, new_r, nzbT, cnt, list);
        hipLaunchKernelGGL(mfma_gemm2, dim3(256), dim3(512), 0, stream,
                           nzbT, woHT, out, new_out);
    } else {
        dim3 blk(256);
        hipLaunchKernelGGL(lsnn_gemm1, dim3(UNITS / BN, B_SZ / BM), blk, 0, stream,
                           x, z, w_in, w_rec, v, r, b, new_z, new_v, new_r, new_b);
        hipLaunchKernelGGL(lsnn_gemm2, dim3(N_OUT / BN, B_SZ / BM), blk, 0, stream,
                           new_z, w_out, out, new_out);
    }
}

// Round 16
// 229.645 us; speedup vs baseline: 1.0297x; 1.0297x over previous
//
#include <hip/hip_runtime.h>
#include <math.h>

// ================= problem constants =================
#define B_SZ   4096
#define UNITS  2048
#define N_IN   1024
#define N_OUT  1024
#define N_LIF  1024

#define DECAY_C   0.951229424500714f     // exp(-1/20)
#define KAPPA_C   0.951229424500714f     // exp(-1/20)
#define DECAYB_C  0.9983347214509387f    // exp(-1/600)
#define THR_C     0.4f
#define BETA_C    1.6f
#define NREF_C    5.0f
#define TAU_C     3e-3f                  // fixup band (~7.5 sigma of fp16 GEMM noise)
#define FIX_CAP   131072
#define NFIXWAVES 2048

typedef _Float16 half8 __attribute__((ext_vector_type(8)));
typedef float  f32x4  __attribute__((ext_vector_type(4)));
typedef unsigned short ushort_t;
typedef unsigned short us8 __attribute__((ext_vector_type(8)));
typedef __bf16 bf16x8 __attribute__((ext_vector_type(8)));

// ---------- conversion helpers ----------
__device__ __forceinline__ unsigned short f2bf(float f) {   // RNE bf16
    unsigned int u = __float_as_uint(f);
    unsigned int r = (u + 0x7fffu + ((u >> 16) & 1u)) >> 16;
    return (unsigned short)r;
}
__device__ __forceinline__ unsigned short f2h(float f) {    // RNE fp16
    _Float16 h = (_Float16)f;
    return __builtin_bit_cast(unsigned short, h);
}

__device__ __forceinline__ void gload_lds16(const ushort_t* g, ushort_t* l) {
    __builtin_amdgcn_global_load_lds(
        (const __attribute__((address_space(1))) unsigned int*)g,
        (__attribute__((address_space(3))) unsigned int*)l, 16, 0, 0);
}

__device__ __forceinline__ double shflxor_d(double x, int m) {
    long long vl = __double_as_longlong(x);
    int lo = (int)(vl & 0xffffffffLL), hi = (int)(vl >> 32);
    lo = __shfl_xor(lo, m, 64);
    hi = __shfl_xor(hi, m, 64);
    return __longlong_as_double(((long long)hi << 32) | (unsigned int)(unsigned)lo);
}

// ================= fused prep (all conversions in one kernel) ==============
// Panel per (blk, kpanel): [c:8][row:128][e:8] = 8192 elems = 16KB.

__device__ __forceinline__ void tileA16_body(const float* __restrict__ src, int K,
                                             ushort_t* __restrict__ dst,
                                             int rb, int kp, int tid) {
    const int KP = K >> 6;
    size_t base = ((size_t)rb * KP + kp) * 8192;
#pragma unroll
    for (int it = 0; it < 4; ++it) {
        int unit = it * 256 + tid;
        int c = unit >> 7, row = unit & 127;
        const float* s = src + (size_t)(rb * 128 + row) * K + kp * 64 + c * 8;
        float4 a  = *reinterpret_cast<const float4*>(s);
        float4 b4 = *reinterpret_cast<const float4*>(s + 4);
        float vals[8] = {a.x, a.y, a.z, a.w, b4.x, b4.y, b4.z, b4.w};
        us8 h;
#pragma unroll
        for (int e = 0; e < 8; ++e) h[e] = f2h(vals[e]);
        *reinterpret_cast<us8*>(dst + base + (size_t)c * 1024 + row * 8) = h;
    }
}

__device__ __forceinline__ void tileW16_body(const float* __restrict__ src, int N, int K,
                                             ushort_t* __restrict__ dst,
                                             int cb, int kp, int tid) {
    const int KP = K >> 6;
    size_t base = ((size_t)cb * KP + kp) * 8192;
#pragma unroll
    for (int it = 0; it < 4; ++it) {
        int unit = it * 256 + tid;
        int c = unit >> 7, n = unit & 127;
        const float* s = src + (size_t)(kp * 64 + c * 8) * N + cb * 128 + n;
        us8 h;
#pragma unroll
        for (int e = 0; e < 8; ++e) h[e] = f2h(s[(size_t)e * N]);
        *reinterpret_cast<us8*>(dst + base + (size_t)c * 1024 + n * 8) = h;
    }
}

__device__ __forceinline__ void tileWbf_body(const float* __restrict__ src, int N, int K,
                                             ushort_t* __restrict__ dst,
                                             int cb, int kp, int tid) {
    const int KP = K >> 6;
    size_t base = ((size_t)cb * KP + kp) * 8192;
#pragma unroll
    for (int it = 0; it < 4; ++it) {
        int unit = it * 256 + tid;
        int c = unit >> 7, n = unit & 127;
        const float* s = src + (size_t)(kp * 64 + c * 8) * N + cb * 128 + n;
        us8 h;
#pragma unroll
        for (int e = 0; e < 8; ++e) h[e] = f2bf(s[(size_t)e * N]);
        *reinterpret_cast<us8*>(dst + base + (size_t)c * 1024 + n * 8) = h;
    }
}

__global__ __launch_bounds__(256)
void prep_all(const float* __restrict__ x, const float* __restrict__ z,
              const float* __restrict__ w_in, const float* __restrict__ w_rec,
              const float* __restrict__ w_out,
              ushort_t* __restrict__ xhT, ushort_t* __restrict__ zbT,
              ushort_t* __restrict__ wiT, ushort_t* __restrict__ wrT,
              ushort_t* __restrict__ woHT, float* __restrict__ wiT32,
              unsigned* __restrict__ cnt) {
    __shared__ float tile[64][65];
    const int bid = blockIdx.x, tid = threadIdx.x;
    if (bid == 0 && tid == 0) *cnt = 0;

    if (bid < 512) {                       // x -> fp16 tiles (32 x 16)
        tileA16_body(x, N_IN, xhT, bid & 31, bid >> 5, tid);
    } else if (bid < 1536) {               // z -> fp16 tiles (32 x 32)
        int u = bid - 512;
        tileA16_body(z, UNITS, zbT, u & 31, u >> 5, tid);
    } else if (bid < 1792) {               // w_in -> fp16 W^T (16 x 16)
        int u = bid - 1536;
        tileW16_body(w_in, UNITS, N_IN, wiT, u & 15, u >> 4, tid);
    } else if (bid < 2304) {               // w_rec -> fp16 W^T (16 x 32)
        int u = bid - 1792;
        tileW16_body(w_rec, UNITS, UNITS, wrT, u & 15, u >> 4, tid);
    } else if (bid < 2560) {               // w_out -> bf16 W^T (8 x 32)
        int u = bid - 2304;
        tileWbf_body(w_out, N_OUT, UNITS, woHT, u & 7, u >> 3, tid);
    } else {                               // w_in fp32 transpose (32 x 16)
        int u = bid - 2560;
        const int n0 = (u & 31) * 64, k0 = (u >> 5) * 64;
        const int tr = tid >> 4, tc = tid & 15;
#pragma unroll
        for (int i = 0; i < 4; ++i) {
            int rr = tr + i * 16;
            float4 v = *reinterpret_cast<const float4*>(
                &w_in[(size_t)(k0 + rr) * UNITS + n0 + tc * 4]);
            tile[rr][tc * 4 + 0] = v.x; tile[rr][tc * 4 + 1] = v.y;
            tile[rr][tc * 4 + 2] = v.z; tile[rr][tc * 4 + 3] = v.w;
        }
        __syncthreads();
#pragma unroll
        for (int i = 0; i < 4; ++i) {
            int nl = tr + i * 16;
            float4 o;
            o.x = tile[tc * 4 + 0][nl]; o.y = tile[tc * 4 + 1][nl];
            o.z = tile[tc * 4 + 2][nl]; o.w = tile[tc * 4 + 3][nl];
            *reinterpret_cast<float4*>(&wiT32[(size_t)(n0 + nl) * N_IN + k0 + tc * 4]) = o;
        }
    }
}

// ====== MFMA GEMM1 fp16 (48 steps: x16*wi16 + z16*wr16), 8x8 XCD tiles =====
__device__ __forceinline__ void resolve1(
    int t, int rby, int cbx,
    const ushort_t* xhT, const ushort_t* zbT,
    const ushort_t* wiT, const ushort_t* wrT,
    const ushort_t*& a, const ushort_t*& bb) {
    if (t < 16) { a = xhT + ((size_t)rby * 16 + t) * 8192;
                  bb = wiT + ((size_t)cbx * 16 + t) * 8192; }
    else        { a = zbT + ((size_t)rby * 32 + t - 16) * 8192;
                  bb = wrT + ((size_t)cbx * 32 + t - 16) * 8192; }
}

__global__ __launch_bounds__(256)
void mfma_gemm1(const ushort_t* __restrict__ xhT, const ushort_t* __restrict__ zbT,
                const ushort_t* __restrict__ wiT, const ushort_t* __restrict__ wrT,
                const float* __restrict__ z, const float* __restrict__ v,
                const float* __restrict__ r, const float* __restrict__ b,
                float* __restrict__ oz, float* __restrict__ ov,
                float* __restrict__ orr, float* __restrict__ ob,
                ushort_t* __restrict__ nzbT,
                unsigned* __restrict__ cnt, unsigned* __restrict__ list) {
    __shared__ ushort_t As[2][8192];
    __shared__ ushort_t Bs[2][8192];
    const int t = threadIdx.x, lane = t & 63, w = t >> 6;
    const int wm = w >> 1, wn = w & 1;
    // 8x8 per-XCD super-tiles: XCD x owns rby in [ (x>>1)*8, +8 ), cbx in [ (x&1)*8, +8 )
    const int bid = blockIdx.x;
    const int xcd = bid & 7, ii = bid >> 3;
    const int rby = (xcd >> 1) * 8 + (ii >> 3);
    const int cbx = (xcd & 1) * 8 + (ii & 7);
    const int row0 = rby * 128, col0 = cbx * 128;
    const int l4 = lane >> 4, l15 = lane & 15;

    f32x4 acc[4][4];
#pragma unroll
    for (int m = 0; m < 4; ++m)
#pragma unroll
        for (int n = 0; n < 4; ++n)
#pragma unroll
            for (int i = 0; i < 4; ++i) acc[m][n][i] = 0.f;

    auto stage = [&](const ushort_t* aB, const ushort_t* bB, int buf) {
#pragma unroll
        for (int c = 0; c < 4; ++c) {
            int ch = w * 4 + c;                   // 16 chunks of 1KB
            gload_lds16(aB + ch * 512 + lane * 8, &As[buf][ch * 512]);
            gload_lds16(bB + ch * 512 + lane * 8, &Bs[buf][ch * 512]);
        }
    };

    {   // prologue
        const ushort_t *a, *bb;
        resolve1(0, rby, cbx, xhT, zbT, wiT, wrT, a, bb);
        stage(a, bb, 0);
    }
    __syncthreads();

    int cur = 0;
    for (int step = 0; step < 48; ++step) {
        if (step + 1 < 48) {
            const ushort_t *a, *bb;
            resolve1(step + 1, rby, cbx, xhT, zbT, wiT, wrT, a, bb);
            stage(a, bb, cur ^ 1);
        }
        const ushort_t* Ab = As[cur];
        const ushort_t* Bb = Bs[cur];
#pragma unroll
        for (int kk = 0; kk < 2; ++kk) {
            half8 af[4], bfr[4];
            const int cBase = (kk * 4 + l4) * 1024;     // [c][row][8] layout
#pragma unroll
            for (int m = 0; m < 4; ++m)
                af[m] = *reinterpret_cast<const half8*>(Ab + cBase + (wm * 64 + m * 16 + l15) * 8);
#pragma unroll
            for (int n = 0; n < 4; ++n)
                bfr[n] = *reinterpret_cast<const half8*>(Bb + cBase + (wn * 64 + n * 16 + l15) * 8);
#pragma unroll
            for (int m = 0; m < 4; ++m)
#pragma unroll
                for (int n = 0; n < 4; ++n)
                    acc[m][n] = __builtin_amdgcn_mfma_f32_16x16x32_f16(
                        af[m], bfr[n], acc[m][n], 0, 0, 0);
        }
        __syncthreads();
        cur ^= 1;
    }
    // K-loop done; final barrier above means no wave still reads As/Bs.
    // Reuse As (32KB) as the block's bf16 new_z tile [128 rows][128 cols].
    ushort_t* ztile = &As[0][0];

    // ---- fused LSNN state-update epilogue (wave-aggregated candidate alloc) ----
    unsigned long long pack = 0ull;
    int ncand = 0;
#pragma unroll
    for (int m = 0; m < 4; ++m)
#pragma unroll
        for (int i = 0; i < 4; ++i) {
            int grow = row0 + wm * 64 + m * 16 + l4 * 4 + i;
            size_t rbase = (size_t)grow * UNITS;
#pragma unroll
            for (int n = 0; n < 4; ++n) {
                int gcol = col0 + wn * 64 + n * 16 + l15;
                size_t idx = rbase + gcol;
                float it = acc[m][n][i];
                float zv = z[idx], bv = b[idx], vv = v[idx], rv = r[idx];
                float beta = (gcol < N_LIF) ? 0.f : BETA_C;
                float nb = DECAYB_C * bv + zv;
                float thr = THR_C + nb * beta;
                float nv = DECAY_C * vv + it - zv * THR_C;
                if (rv <= 0.f && fabsf(nv - thr) < TAU_C) {
                    int code = (m << 4) | (i << 2) | n;
                    if (ncand < 10) {
                        pack |= (unsigned long long)code << (6 * ncand);
                        ++ncand;
                    } else {            // overflow fallback (P ~ 0)
                        unsigned slot = atomicAdd(cnt, 1u);
                        if (slot < FIX_CAP)
                            list[slot] = ((unsigned)grow << 11) | (unsigned)gcol;
                    }
                }
                float nz = (rv > 0.f) ? 0.f : ((nv - thr > 0.f) ? 1.f : 0.f);
                float nr = fminf(fmaxf(rv + NREF_C * nz - 1.f, 0.f), NREF_C);
                oz[idx] = nz; ov[idx] = nv; orr[idx] = nr; ob[idx] = nb;
                ztile[(grow & 127) * 128 + (gcol & 127)]
                    = (nz > 0.f) ? (unsigned short)0x3F80 : (unsigned short)0;  // bf16 1.0
            }
        }

    unsigned scan = (unsigned)ncand;
#pragma unroll
    for (int off = 1; off < 64; off <<= 1) {
        unsigned up = (unsigned)__shfl_up((int)scan, off, 64);
        if (lane >= off) scan += up;
    }
    unsigned total = (unsigned)__shfl((int)scan, 63, 64);
    if (total > 0) {
        unsigned basev = 0;
        if (lane == 63) basev = atomicAdd(cnt, total);
        basev = (unsigned)__shfl((int)basev, 63, 64);
        unsigned myoff = basev + scan - (unsigned)ncand;
        for (int j = 0; j < ncand; ++j) {
            int code = (int)((pack >> (6 * j)) & 63ull);
            int m = code >> 4, i = (code >> 2) & 3, n = code & 3;
            int grow = row0 + wm * 64 + m * 16 + l4 * 4 + i;
            int gcol = col0 + wn * 64 + n * 16 + l15;
            unsigned slot = myoff + (unsigned)j;
            if (slot < FIX_CAP)
                list[slot] = ((unsigned)grow << 11) | (unsigned)gcol;
        }
    }

    // ---- cooperative coalesced writeout of the two 16KB nzbT panels ----
    // Region = panels kp = cbx*2, cbx*2+1 (contiguous). Linear index d:
    //   d = (kp&1)*8192 + c2*1024 + row*8 + e2  <=>  ztile[row*128 + (gcol&127)]
    __syncthreads();
    {
        ushort_t* dst = nzbT + ((size_t)rby * 32 + cbx * 2) * 8192;
        int d0 = t * 64;
#pragma unroll
        for (int j = 0; j < 8; ++j) {
            int d = d0 + j * 8;
            int p = d >> 13, c2 = (d >> 10) & 7, row = (d >> 3) & 127;
            us8 vsrc = *reinterpret_cast<const us8*>(&ztile[row * 128 + p * 64 + c2 * 8]);
            *reinterpret_cast<us8*>(&dst[d]) = vsrc;
        }
    }
}

// ================= deferred exact fixup (one wave per candidate, fp64) ======
__global__ __launch_bounds__(256)
void fixup_kernel(const float* __restrict__ x, const float* __restrict__ z,
                  const float* __restrict__ wiT32, const float* __restrict__ wr,
                  const float* __restrict__ v, const float* __restrict__ r,
                  const float* __restrict__ b,
                  float* __restrict__ oz, float* __restrict__ ov,
                  float* __restrict__ orr, ushort_t* __restrict__ nzbT,
                  const unsigned* __restrict__ cnt, const unsigned* __restrict__ list) {
    unsigned total = *cnt;
    if (total > FIX_CAP) total = FIX_CAP;
    const int lane = threadIdx.x & 63;
    const int wid = blockIdx.x * 4 + (threadIdx.x >> 6);
    for (unsigned ci = wid; ci < total; ci += NFIXWAVES) {
        unsigned enc = list[ci];
        int grow = (int)(enc >> 11), gcol = (int)(enc & 2047);
        const float* xr = x + (size_t)grow * N_IN;
        const float* zr = z + (size_t)grow * UNITS;
        const float* wc = wiT32 + (size_t)gcol * N_IN;
        double acc = 0.0;
#pragma unroll 8
        for (int j = 0; j < 16; ++j) {
            int k = lane + j * 64;
            acc = fma((double)xr[k], (double)wc[k], acc);
        }
#pragma unroll 4
        for (int j = 0; j < 32; ++j) {
            int k = lane + j * 64;
            float zk = zr[k];
            if (zk != 0.f)
                acc = fma((double)zk, (double)wr[(size_t)k * UNITS + gcol], acc);
        }
#pragma unroll
        for (int off = 32; off >= 1; off >>= 1) acc += shflxor_d(acc, off);
        if (lane == 0) {
            size_t idx = (size_t)grow * UNITS + gcol;
            float zv = z[idx], bv = b[idx], vv = v[idx], rv = r[idx];
            float beta = (gcol < N_LIF) ? 0.f : BETA_C;
            float nb = DECAYB_C * bv + zv;
            float thr = THR_C + nb * beta;
            double nvd = (double)DECAY_C * (double)vv + acc - (double)zv * (double)THR_C;
            float nz = (rv > 0.f) ? 0.f : ((nvd - (double)thr > 0.0) ? 1.f : 0.f);
            float nr = fminf(fmaxf(rv + NREF_C * nz - 1.f, 0.f), NREF_C);
            oz[idx] = nz; ov[idx] = (float)nvd; orr[idx] = nr;
            int kp2 = gcol >> 6, c2 = (gcol & 63) >> 3, e2 = gcol & 7;
            nzbT[((size_t)(grow >> 7) * 32 + kp2) * 8192 + c2 * 1024 + (grow & 127) * 8 + e2]
                = (nz > 0.f) ? (unsigned short)0x3F80 : (unsigned short)0;
        }
    }
}

// ====== MFMA GEMM2 bf16, split-K-in-block (2 wave-groups x 16 steps) ======
__global__ __launch_bounds__(512)
void mfma_gemm2(const ushort_t* __restrict__ nzbT, const ushort_t* __restrict__ woHT,
                const float* __restrict__ prev, float* __restrict__ nout) {
    __shared__ ushort_t As[2][2][8192];     // [grp][buf]
    __shared__ ushort_t Bs[2][2][8192];
    const int t = threadIdx.x, lane = t & 63, w8 = t >> 6;
    const int grp = w8 >> 2, w = w8 & 3;
    const int wm = w >> 1, wn = w & 1;
    const int bid = blockIdx.x;
    const int swz = (bid & 7) * 32 + (bid >> 3);   // 256 blocks, bijective
    const int rby = swz >> 3, cbx = swz & 7;
    const int row0 = rby * 128, col0 = cbx * 128;
    const int l4 = lane >> 4, l15 = lane & 15;

    f32x4 acc[4][4];
#pragma unroll
    for (int m = 0; m < 4; ++m)
#pragma unroll
        for (int n = 0; n < 4; ++n)
#pragma unroll
            for (int i = 0; i < 4; ++i) acc[m][n][i] = 0.f;

    auto stage = [&](int sc, int buf) {
        const ushort_t* aB = nzbT + ((size_t)rby * 32 + sc) * 8192;
        const ushort_t* bB = woHT + ((size_t)cbx * 32 + sc) * 8192;
#pragma unroll
        for (int c = 0; c < 4; ++c) {
            int ch = w * 4 + c;
            gload_lds16(aB + ch * 512 + lane * 8, &As[grp][buf][ch * 512]);
            gload_lds16(bB + ch * 512 + lane * 8, &Bs[grp][buf][ch * 512]);
        }
    };

    stage(grp * 16, 0);
    __syncthreads();
    int cur = 0;
    for (int step = 0; step < 16; ++step) {
        if (step + 1 < 16) stage(grp * 16 + step + 1, cur ^ 1);
        const ushort_t* Ab = As[grp][cur];
        const ushort_t* Bb = Bs[grp][cur];
#pragma unroll
        for (int kk = 0; kk < 2; ++kk) {
            bf16x8 af[4], bfr[4];
            const int cBase = (kk * 4 + l4) * 1024;
#pragma unroll
            for (int m = 0; m < 4; ++m)
                af[m] = *reinterpret_cast<const bf16x8*>(Ab + cBase + (wm * 64 + m * 16 + l15) * 8);
#pragma unroll
            for (int n = 0; n < 4; ++n)
                bfr[n] = *reinterpret_cast<const bf16x8*>(Bb + cBase + (wn * 64 + n * 16 + l15) * 8);
#pragma unroll
            for (int m = 0; m < 4; ++m)
#pragma unroll
                for (int n = 0; n < 4; ++n)
                    acc[m][n] = __builtin_amdgcn_mfma_f32_16x16x32_bf16(
                        af[m], bfr[n], acc[m][n], 0, 0, 0);
        }
        __syncthreads();
        cur ^= 1;
    }

    // combine: group1 partials -> LDS (reuse As, 128*128 f32 = 64KB), group0 sums
    float* part = reinterpret_cast<float*>(As);
    if (grp == 1) {
#pragma unroll
        for (int m = 0; m < 4; ++m)
#pragma unroll
            for (int i = 0; i < 4; ++i) {
                int lr = wm * 64 + m * 16 + l4 * 4 + i;
#pragma unroll
                for (int n = 0; n < 4; ++n)
                    part[lr * 128 + wn * 64 + n * 16 + l15] = acc[m][n][i];
            }
    }
    __syncthreads();
    if (grp == 0) {
#pragma unroll
        for (int m = 0; m < 4; ++m)
#pragma unroll
            for (int i = 0; i < 4; ++i) {
                int lr = wm * 64 + m * 16 + l4 * 4 + i;
                size_t rbase = (size_t)(row0 + lr) * N_OUT;
#pragma unroll
                for (int n = 0; n < 4; ++n) {
                    int lc = wn * 64 + n * 16 + l15;
                    size_t idx = rbase + col0 + lc;
                    nout[idx] = KAPPA_C * prev[idx] + acc[m][n][i] + part[lr * 128 + lc];
                }
            }
    }
}

// ================= fp32 fallback (round-1 kernel; used if ws too small) =====
#define BM 128
#define BN 128
#define BK 16
#define TM 8
#define TN 8

__global__ __launch_bounds__(256)
void lsnn_gemm1(const float* __restrict__ x, const float* __restrict__ z,
                const float* __restrict__ w_in, const float* __restrict__ w_rec,
                const float* __restrict__ v, const float* __restrict__ r,
                const float* __restrict__ b,
                float* __restrict__ out_z, float* __restrict__ out_v,
                float* __restrict__ out_r, float* __restrict__ out_b) {
    __shared__ float As_[BK][BM + 4];
    __shared__ float Bs_[BK][BN + 4];
    const int bx = blockIdx.x, by = blockIdx.y, t = threadIdx.x;
    const int tx = t & 15, ty = t >> 4;
    const int row0 = by * BM, col0 = bx * BN;
    float acc[TM][TN];
#pragma unroll
    for (int i = 0; i < TM; ++i)
#pragma unroll
        for (int j = 0; j < TN; ++j) acc[i][j] = 0.f;
    for (int k0 = 0; k0 < N_IN + UNITS; k0 += BK) {
#pragma unroll
        for (int l = 0; l < 2; ++l) {
            int e = t + l * 256, arow = e >> 2, acol = (e & 3) * 4, gk = k0 + acol;
            const float* src = (gk < N_IN) ? (x + (size_t)(row0 + arow) * N_IN + gk)
                                           : (z + (size_t)(row0 + arow) * UNITS + (gk - N_IN));
            float4 av = *reinterpret_cast<const float4*>(src);
            As_[acol + 0][arow] = av.x; As_[acol + 1][arow] = av.y;
            As_[acol + 2][arow] = av.z; As_[acol + 3][arow] = av.w;
        }
#pragma unroll
        for (int l = 0; l < 2; ++l) {
            int e = t + l * 256, brow = e >> 5, bcol = (e & 31) * 4, gk = k0 + brow;
            const float* src = (gk < N_IN) ? (w_in + (size_t)gk * UNITS + col0 + bcol)
                                           : (w_rec + (size_t)(gk - N_IN) * UNITS + col0 + bcol);
            *reinterpret_cast<float4*>(&Bs_[brow][bcol]) = *reinterpret_cast<const float4*>(src);
        }
        __syncthreads();
#pragma unroll
        for (int kk = 0; kk < BK; ++kk) {
            float ra[TM], rb[TN];
#pragma unroll
            for (int i = 0; i < TM; ++i) ra[i] = As_[kk][ty * TM + i];
#pragma unroll
            for (int j = 0; j < TN; ++j) rb[j] = Bs_[kk][tx * TN + j];
#pragma unroll
            for (int i = 0; i < TM; ++i)
#pragma unroll
                for (int j = 0; j < TN; ++j) acc[i][j] = fmaf(ra[i], rb[j], acc[i][j]);
        }
        __syncthreads();
    }
#pragma unroll
    for (int i = 0; i < TM; ++i) {
        int gi = row0 + ty * TM + i;
        size_t base = (size_t)gi * UNITS;
#pragma unroll
        for (int j = 0; j < TN; ++j) {
            int gj = col0 + tx * TN + j;
            size_t idx = base + gj;
            float zv = z[idx], bv = b[idx], vv = v[idx], rv = r[idx];
            float beta = (gj < N_LIF) ? 0.f : BETA_C;
            float nb = DECAYB_C * bv + zv;
            float thr_ac = THR_C + nb * beta;
            float nv = DECAY_C * vv + acc[i][j] - zv * THR_C;
            float nz = (rv > 0.f) ? 0.f : (((nv - thr_ac) > 0.f) ? 1.f : 0.f);
            float nr = fminf(fmaxf(rv + NREF_C * nz - 1.f, 0.f), NREF_C);
            out_z[idx] = nz; out_v[idx] = nv; out_r[idx] = nr; out_b[idx] = nb;
        }
    }
}

__global__ __launch_bounds__(256)
void lsnn_gemm2(const float* __restrict__ nz, const float* __restrict__ w_out,
                const float* __restrict__ prev_out, float* __restrict__ new_out) {
    __shared__ float As_[BK][BM + 4];
    __shared__ float Bs_[BK][BN + 4];
    const int bx = blockIdx.x, by = blockIdx.y, t = threadIdx.x;
    const int tx = t & 15, ty = t >> 4;
    const int row0 = by * BM, col0 = bx * BN;
    float acc[TM][TN];
#pragma unroll
    for (int i = 0; i < TM; ++i)
#pragma unroll
        for (int j = 0; j < TN; ++j) acc[i][j] = 0.f;
    for (int k0 = 0; k0 < UNITS; k0 += BK) {
#pragma unroll
        for (int l = 0; l < 2; ++l) {
            int e = t + l * 256, arow = e >> 2, acol = (e & 3) * 4, gk = k0 + acol;
            float4 av = *reinterpret_cast<const float4*>(nz + (size_t)(row0 + arow) * UNITS + gk);
            As_[acol + 0][arow] = av.x; As_[acol + 1][arow] = av.y;
            As_[acol + 2][arow] = av.z; As_[acol + 3][arow] = av.w;
        }
#pragma unroll
        for (int l = 0; l < 2; ++l) {
            int e = t + l * 256, brow = e >> 5, bcol = (e & 31) * 4, gk = k0 + brow;
            *reinterpret_cast<float4*>(&Bs_[brow][bcol]) =
                *reinterpret_cast<const float4*>(w_out + (size_t)gk * N_OUT + col0 + bcol);
        }
        __syncthreads();
#pragma unroll
        for (int kk = 0; kk < BK; ++kk) {
            float ra[TM], rb[TN];
#pragma unroll
            for (int i = 0; i < TM; ++i) ra[i] = As_[kk][ty * TM + i];
#pragma unroll
            for (int j = 0; j < TN; ++j) rb[j] = Bs_[kk][tx * TN + j];
#pragma unroll
            for (int i = 0; i < TM; ++i)
#pragma unroll
                for (int j = 0; j < TN; ++j) acc[i][j] = fmaf(ra[i], rb[j], acc[i][j]);
        }
        __syncthreads();
    }
#pragma unroll
    for (int i = 0; i < TM; ++i) {
        int gi = row0 + ty * TM + i;
        size_t base = (size_t)gi * N_OUT;
#pragma unroll
        for (int j = 0; j < TN; ++j) {
            int gj = col0 + tx * TN + j;
            size_t idx = base + gj;
            new_out[idx] = KAPPA_C * prev_out[idx] + acc[i][j];
        }
    }
}

// ================= launch =================
extern "C" void kernel_launch(void* const* d_in, const int* in_sizes, int n_in,
                              void* d_out, int out_size, void* d_ws, size_t ws_size,
                              hipStream_t stream) {
    const float* x     = (const float*)d_in[0];
    const float* v     = (const float*)d_in[1];
    const float* z     = (const float*)d_in[2];
    const float* r     = (const float*)d_in[3];
    const float* out   = (const float*)d_in[4];
    const float* b     = (const float*)d_in[5];
    const float* w_in  = (const float*)d_in[6];
    const float* w_rec = (const float*)d_in[7];
    const float* w_out = (const float*)d_in[8];

    float* o       = (float*)d_out;
    float* new_out = o;
    float* new_z   = o + (size_t)B_SZ * N_OUT;
    float* new_v   = new_z + (size_t)B_SZ * UNITS;
    float* new_r   = new_v + (size_t)B_SZ * UNITS;
    float* new_b   = new_r + (size_t)B_SZ * UNITS;

    const size_t MB = 1u << 20;
    const size_t need = 66 * MB;
    if (ws_size >= need) {
        char* wsb = (char*)d_ws;
        ushort_t* xhT   = (ushort_t*)(wsb + 0 * MB);    // 8 MB  (fp16 x)
        ushort_t* zbT   = (ushort_t*)(wsb + 8 * MB);    // 16 MB (fp16 z, exact)
        ushort_t* nzbT  = (ushort_t*)(wsb + 24 * MB);   // 16 MB (bf16 new_z, tiled)
        ushort_t* wiT   = (ushort_t*)(wsb + 40 * MB);   // 4 MB  (fp16 w_in^T)
        ushort_t* wrT   = (ushort_t*)(wsb + 44 * MB);   // 8 MB  (fp16 w_rec^T)
        ushort_t* woHT  = (ushort_t*)(wsb + 52 * MB);   // 4 MB  (bf16 w_out^T)
        float*    wiT32 = (float*)   (wsb + 56 * MB);   // 8 MB  (fp32 w_in^T)
        unsigned* cnt   = (unsigned*)(wsb + 64 * MB);
        unsigned* list  = (unsigned*)(wsb + 64 * MB + 4096);  // 512 KB

        hipLaunchKernelGGL(prep_all, dim3(3072), dim3(256), 0, stream,
                           x, z, w_in, w_rec, w_out,
                           xhT, zbT, wiT, wrT, woHT, wiT32, cnt);
        hipLaunchKernelGGL(mfma_gemm1, dim3(512), dim3(256), 0, stream,
                           xhT, zbT, wiT, wrT,
                           z, v, r, b, new_z, new_v, new_r, new_b, nzbT, cnt, list);
        hipLaunchKernelGGL(fixup_kernel, dim3(NFIXWAVES / 4), dim3(256), 0, stream,
                           x, z, wiT32, w_rec, v, r, b, new_z, new_v, new_r, nzbT, cnt, list);
        hipLaunchKernelGGL(mfma_gemm2, dim3(256), dim3(512), 0, stream,
                           nzbT, woHT, out, new_out);
    } else {
        dim3 blk(256);
        hipLaunchKernelGGL(lsnn_gemm1, dim3(UNITS / BN, B_SZ / BM), blk, 0, stream,
                           x, z, w_in, w_rec, v, r, b, new_z, new_v, new_r, new_b);
        hipLaunchKernelGGL(lsnn_gemm2, dim3(N_OUT / BN, B_SZ / BM), blk, 0, stream,
                           new_z, w_out, out, new_out);
    }
}

// Round 17
// 224.542 us; speedup vs baseline: 1.0531x; 1.0227x over previous
//
#include <hip/hip_runtime.h>
#include <math.h>

// ================= problem constants =================
#define B_SZ   4096
#define UNITS  2048
#define N_IN   1024
#define N_OUT  1024
#define N_LIF  1024

#define DECAY_C   0.951229424500714f     // exp(-1/20)
#define KAPPA_C   0.951229424500714f     // exp(-1/20)
#define DECAYB_C  0.9983347214509387f    // exp(-1/600)
#define THR_C     0.4f
#define BETA_C    1.6f
#define NREF_C    5.0f
#define TAU_C     3e-3f                  // fixup band (~7.5 sigma of fp16 GEMM noise)
#define FIX_CAP   131072
#define NFIXWAVES 2048

typedef _Float16 half8 __attribute__((ext_vector_type(8)));
typedef float  f32x4  __attribute__((ext_vector_type(4)));
typedef unsigned short ushort_t;
typedef unsigned short us8 __attribute__((ext_vector_type(8)));
typedef __bf16 bf16x8 __attribute__((ext_vector_type(8)));

// ---------- conversion helpers ----------
__device__ __forceinline__ unsigned short f2bf(float f) {   // RNE bf16
    unsigned int u = __float_as_uint(f);
    unsigned int r = (u + 0x7fffu + ((u >> 16) & 1u)) >> 16;
    return (unsigned short)r;
}
__device__ __forceinline__ unsigned short f2h(float f) {    // RNE fp16
    _Float16 h = (_Float16)f;
    return __builtin_bit_cast(unsigned short, h);
}

__device__ __forceinline__ void gload_lds16(const ushort_t* g, ushort_t* l) {
    __builtin_amdgcn_global_load_lds(
        (const __attribute__((address_space(1))) unsigned int*)g,
        (__attribute__((address_space(3))) unsigned int*)l, 16, 0, 0);
}

__device__ __forceinline__ double shflxor_d(double x, int m) {
    long long vl = __double_as_longlong(x);
    int lo = (int)(vl & 0xffffffffLL), hi = (int)(vl >> 32);
    lo = __shfl_xor(lo, m, 64);
    hi = __shfl_xor(hi, m, 64);
    return __longlong_as_double(((long long)hi << 32) | (unsigned int)(unsigned)lo);
}

// ================= fused prep (all conversions in one kernel) ==============
// Panel per (blk, kpanel): [c:8][row:128][e:8] = 8192 elems = 16KB.

__device__ __forceinline__ void tileA16_body(const float* __restrict__ src, int K,
                                             ushort_t* __restrict__ dst,
                                             int rb, int kp, int tid) {
    const int KP = K >> 6;
    size_t base = ((size_t)rb * KP + kp) * 8192;
#pragma unroll
    for (int it = 0; it < 4; ++it) {
        int unit = it * 256 + tid;
        int c = unit >> 7, row = unit & 127;
        const float* s = src + (size_t)(rb * 128 + row) * K + kp * 64 + c * 8;
        float4 a  = *reinterpret_cast<const float4*>(s);
        float4 b4 = *reinterpret_cast<const float4*>(s + 4);
        float vals[8] = {a.x, a.y, a.z, a.w, b4.x, b4.y, b4.z, b4.w};
        us8 h;
#pragma unroll
        for (int e = 0; e < 8; ++e) h[e] = f2h(vals[e]);
        *reinterpret_cast<us8*>(dst + base + (size_t)c * 1024 + row * 8) = h;
    }
}

__device__ __forceinline__ void tileW16_body(const float* __restrict__ src, int N, int K,
                                             ushort_t* __restrict__ dst,
                                             int cb, int kp, int tid) {
    const int KP = K >> 6;
    size_t base = ((size_t)cb * KP + kp) * 8192;
#pragma unroll
    for (int it = 0; it < 4; ++it) {
        int unit = it * 256 + tid;
        int c = unit >> 7, n = unit & 127;
        const float* s = src + (size_t)(kp * 64 + c * 8) * N + cb * 128 + n;
        us8 h;
#pragma unroll
        for (int e = 0; e < 8; ++e) h[e] = f2h(s[(size_t)e * N]);
        *reinterpret_cast<us8*>(dst + base + (size_t)c * 1024 + n * 8) = h;
    }
}

__device__ __forceinline__ void tileWbf_body(const float* __restrict__ src, int N, int K,
                                             ushort_t* __restrict__ dst,
                                             int cb, int kp, int tid) {
    const int KP = K >> 6;
    size_t base = ((size_t)cb * KP + kp) * 8192;
#pragma unroll
    for (int it = 0; it < 4; ++it) {
        int unit = it * 256 + tid;
        int c = unit >> 7, n = unit & 127;
        const float* s = src + (size_t)(kp * 64 + c * 8) * N + cb * 128 + n;
        us8 h;
#pragma unroll
        for (int e = 0; e < 8; ++e) h[e] = f2bf(s[(size_t)e * N]);
        *reinterpret_cast<us8*>(dst + base + (size_t)c * 1024 + n * 8) = h;
    }
}

__global__ __launch_bounds__(256)
void prep_all(const float* __restrict__ x, const float* __restrict__ z,
              const float* __restrict__ w_in, const float* __restrict__ w_rec,
              const float* __restrict__ w_out,
              ushort_t* __restrict__ xhT, ushort_t* __restrict__ zbT,
              ushort_t* __restrict__ wiT, ushort_t* __restrict__ wrT,
              ushort_t* __restrict__ woHT, float* __restrict__ wiT32,
              unsigned* __restrict__ cnt) {
    __shared__ float tile[64][65];
    const int bid = blockIdx.x, tid = threadIdx.x;
    if (bid == 0 && tid == 0) *cnt = 0;

    if (bid < 512) {                       // x -> fp16 tiles (32 x 16)
        tileA16_body(x, N_IN, xhT, bid & 31, bid >> 5, tid);
    } else if (bid < 1536) {               // z -> fp16 tiles (32 x 32)
        int u = bid - 512;
        tileA16_body(z, UNITS, zbT, u & 31, u >> 5, tid);
    } else if (bid < 1792) {               // w_in -> fp16 W^T (16 x 16)
        int u = bid - 1536;
        tileW16_body(w_in, UNITS, N_IN, wiT, u & 15, u >> 4, tid);
    } else if (bid < 2304) {               // w_rec -> fp16 W^T (16 x 32)
        int u = bid - 1792;
        tileW16_body(w_rec, UNITS, UNITS, wrT, u & 15, u >> 4, tid);
    } else if (bid < 2560) {               // w_out -> bf16 W^T (8 x 32)
        int u = bid - 2304;
        tileWbf_body(w_out, N_OUT, UNITS, woHT, u & 7, u >> 3, tid);
    } else {                               // w_in fp32 transpose (32 x 16)
        int u = bid - 2560;
        const int n0 = (u & 31) * 64, k0 = (u >> 5) * 64;
        const int tr = tid >> 4, tc = tid & 15;
#pragma unroll
        for (int i = 0; i < 4; ++i) {
            int rr = tr + i * 16;
            float4 v = *reinterpret_cast<const float4*>(
                &w_in[(size_t)(k0 + rr) * UNITS + n0 + tc * 4]);
            tile[rr][tc * 4 + 0] = v.x; tile[rr][tc * 4 + 1] = v.y;
            tile[rr][tc * 4 + 2] = v.z; tile[rr][tc * 4 + 3] = v.w;
        }
        __syncthreads();
#pragma unroll
        for (int i = 0; i < 4; ++i) {
            int nl = tr + i * 16;
            float4 o;
            o.x = tile[tc * 4 + 0][nl]; o.y = tile[tc * 4 + 1][nl];
            o.z = tile[tc * 4 + 2][nl]; o.w = tile[tc * 4 + 3][nl];
            *reinterpret_cast<float4*>(&wiT32[(size_t)(n0 + nl) * N_IN + k0 + tc * 4]) = o;
        }
    }
}

// ====== MFMA GEMM1 fp16 (48 steps), 8x8 XCD tiles, counted-vmcnt barriers ==
__device__ __forceinline__ void resolve1(
    int t, int rby, int cbx,
    const ushort_t* xhT, const ushort_t* zbT,
    const ushort_t* wiT, const ushort_t* wrT,
    const ushort_t*& a, const ushort_t*& bb) {
    if (t < 16) { a = xhT + ((size_t)rby * 16 + t) * 8192;
                  bb = wiT + ((size_t)cbx * 16 + t) * 8192; }
    else        { a = zbT + ((size_t)rby * 32 + t - 16) * 8192;
                  bb = wrT + ((size_t)cbx * 32 + t - 16) * 8192; }
}

__global__ __launch_bounds__(256)
void mfma_gemm1(const ushort_t* __restrict__ xhT, const ushort_t* __restrict__ zbT,
                const ushort_t* __restrict__ wiT, const ushort_t* __restrict__ wrT,
                const float* __restrict__ z, const float* __restrict__ v,
                const float* __restrict__ r, const float* __restrict__ b,
                float* __restrict__ oz, float* __restrict__ ov,
                float* __restrict__ orr, float* __restrict__ ob,
                ushort_t* __restrict__ nzbT,
                unsigned* __restrict__ cnt, unsigned* __restrict__ list) {
    __shared__ ushort_t As[2][8192];
    __shared__ ushort_t Bs[2][8192];
    const int t = threadIdx.x, lane = t & 63, w = t >> 6;
    const int wm = w >> 1, wn = w & 1;
    const int bid = blockIdx.x;
    const int xcd = bid & 7, ii = bid >> 3;
    const int rby = (xcd >> 1) * 8 + (ii >> 3);
    const int cbx = (xcd & 1) * 8 + (ii & 7);
    const int row0 = rby * 128, col0 = cbx * 128;
    const int l4 = lane >> 4, l15 = lane & 15;

    f32x4 acc[4][4];
#pragma unroll
    for (int m = 0; m < 4; ++m)
#pragma unroll
        for (int n = 0; n < 4; ++n)
#pragma unroll
            for (int i = 0; i < 4; ++i) acc[m][n][i] = 0.f;

    auto stage = [&](const ushort_t* aB, const ushort_t* bB, int buf) {
#pragma unroll
        for (int c = 0; c < 4; ++c) {
            int ch = w * 4 + c;                   // 16 chunks of 1KB
            gload_lds16(aB + ch * 512 + lane * 8, &As[buf][ch * 512]);
            gload_lds16(bB + ch * 512 + lane * 8, &Bs[buf][ch * 512]);
        }
    };

    {   // prologue
        const ushort_t *a, *bb;
        resolve1(0, rby, cbx, xhT, zbT, wiT, wrT, a, bb);
        stage(a, bb, 0);
    }
    __syncthreads();

    int cur = 0;
    for (int step = 0; step < 48; ++step) {
        // T4-minimum: issue next-step prefetch, then wait ONLY for the
        // previous step's 8 loads (counted vmcnt) — the 8 prefetch loads
        // stay in flight across the barrier (never drain to 0 mid-loop).
        if (step + 1 < 48) {
            const ushort_t *a, *bb;
            resolve1(step + 1, rby, cbx, xhT, zbT, wiT, wrT, a, bb);
            stage(a, bb, cur ^ 1);
            asm volatile("s_waitcnt vmcnt(8)" ::: "memory");
        } else {
            asm volatile("s_waitcnt vmcnt(0)" ::: "memory");
        }
        __builtin_amdgcn_s_barrier();
        __builtin_amdgcn_sched_barrier(0);
        const ushort_t* Ab = As[cur];
        const ushort_t* Bb = Bs[cur];
#pragma unroll
        for (int kk = 0; kk < 2; ++kk) {
            half8 af[4], bfr[4];
            const int cBase = (kk * 4 + l4) * 1024;     // [c][row][8] layout
#pragma unroll
            for (int m = 0; m < 4; ++m)
                af[m] = *reinterpret_cast<const half8*>(Ab + cBase + (wm * 64 + m * 16 + l15) * 8);
#pragma unroll
            for (int n = 0; n < 4; ++n)
                bfr[n] = *reinterpret_cast<const half8*>(Bb + cBase + (wn * 64 + n * 16 + l15) * 8);
#pragma unroll
            for (int m = 0; m < 4; ++m)
#pragma unroll
                for (int n = 0; n < 4; ++n)
                    acc[m][n] = __builtin_amdgcn_mfma_f32_16x16x32_f16(
                        af[m], bfr[n], acc[m][n], 0, 0, 0);
        }
        __builtin_amdgcn_s_barrier();               // all reads of buf[cur] done
        __builtin_amdgcn_sched_barrier(0);          // pin next stage below
        cur ^= 1;
    }
    // K-loop done (vmcnt(0) waited on last iter; final barrier passed).
    // Reuse As (32KB) as the block's bf16 new_z tile [128 rows][128 cols].
    ushort_t* ztile = &As[0][0];

    // ---- fused LSNN state-update epilogue (wave-aggregated candidate alloc) ----
    unsigned long long pack = 0ull;
    int ncand = 0;
#pragma unroll
    for (int m = 0; m < 4; ++m)
#pragma unroll
        for (int i = 0; i < 4; ++i) {
            int grow = row0 + wm * 64 + m * 16 + l4 * 4 + i;
            size_t rbase = (size_t)grow * UNITS;
#pragma unroll
            for (int n = 0; n < 4; ++n) {
                int gcol = col0 + wn * 64 + n * 16 + l15;
                size_t idx = rbase + gcol;
                float it = acc[m][n][i];
                float zv = z[idx], bv = b[idx], vv = v[idx], rv = r[idx];
                float beta = (gcol < N_LIF) ? 0.f : BETA_C;
                float nb = DECAYB_C * bv + zv;
                float thr = THR_C + nb * beta;
                float nv = DECAY_C * vv + it - zv * THR_C;
                if (rv <= 0.f && fabsf(nv - thr) < TAU_C) {
                    int code = (m << 4) | (i << 2) | n;
                    if (ncand < 10) {
                        pack |= (unsigned long long)code << (6 * ncand);
                        ++ncand;
                    } else {            // overflow fallback (P ~ 0)
                        unsigned slot = atomicAdd(cnt, 1u);
                        if (slot < FIX_CAP)
                            list[slot] = ((unsigned)grow << 11) | (unsigned)gcol;
                    }
                }
                float nz = (rv > 0.f) ? 0.f : ((nv - thr > 0.f) ? 1.f : 0.f);
                float nr = fminf(fmaxf(rv + NREF_C * nz - 1.f, 0.f), NREF_C);
                oz[idx] = nz; ov[idx] = nv; orr[idx] = nr; ob[idx] = nb;
                ztile[(grow & 127) * 128 + (gcol & 127)]
                    = (nz > 0.f) ? (unsigned short)0x3F80 : (unsigned short)0;  // bf16 1.0
            }
        }

    unsigned scan = (unsigned)ncand;
#pragma unroll
    for (int off = 1; off < 64; off <<= 1) {
        unsigned up = (unsigned)__shfl_up((int)scan, off, 64);
        if (lane >= off) scan += up;
    }
    unsigned total = (unsigned)__shfl((int)scan, 63, 64);
    if (total > 0) {
        unsigned basev = 0;
        if (lane == 63) basev = atomicAdd(cnt, total);
        basev = (unsigned)__shfl((int)basev, 63, 64);
        unsigned myoff = basev + scan - (unsigned)ncand;
        for (int j = 0; j < ncand; ++j) {
            int code = (int)((pack >> (6 * j)) & 63ull);
            int m = code >> 4, i = (code >> 2) & 3, n = code & 3;
            int grow = row0 + wm * 64 + m * 16 + l4 * 4 + i;
            int gcol = col0 + wn * 64 + n * 16 + l15;
            unsigned slot = myoff + (unsigned)j;
            if (slot < FIX_CAP)
                list[slot] = ((unsigned)grow << 11) | (unsigned)gcol;
        }
    }

    // ---- cooperative coalesced writeout of the two 16KB nzbT panels ----
    __syncthreads();
    {
        ushort_t* dst = nzbT + ((size_t)rby * 32 + cbx * 2) * 8192;
        int d0 = t * 64;
#pragma unroll
        for (int j = 0; j < 8; ++j) {
            int d = d0 + j * 8;
            int p = d >> 13, c2 = (d >> 10) & 7, row = (d >> 3) & 127;
            us8 vsrc = *reinterpret_cast<const us8*>(&ztile[row * 128 + p * 64 + c2 * 8]);
            *reinterpret_cast<us8*>(&dst[d]) = vsrc;
        }
    }
}

// ================= deferred exact fixup (one wave per candidate, fp64) ======
__global__ __launch_bounds__(256)
void fixup_kernel(const float* __restrict__ x, const float* __restrict__ z,
                  const float* __restrict__ wiT32, const float* __restrict__ wr,
                  const float* __restrict__ v, const float* __restrict__ r,
                  const float* __restrict__ b,
                  float* __restrict__ oz, float* __restrict__ ov,
                  float* __restrict__ orr, ushort_t* __restrict__ nzbT,
                  const unsigned* __restrict__ cnt, const unsigned* __restrict__ list) {
    unsigned total = *cnt;
    if (total > FIX_CAP) total = FIX_CAP;
    const int lane = threadIdx.x & 63;
    const int wid = blockIdx.x * 4 + (threadIdx.x >> 6);
    for (unsigned ci = wid; ci < total; ci += NFIXWAVES) {
        unsigned enc = list[ci];
        int grow = (int)(enc >> 11), gcol = (int)(enc & 2047);
        const float* xr = x + (size_t)grow * N_IN;
        const float* zr = z + (size_t)grow * UNITS;
        const float* wc = wiT32 + (size_t)gcol * N_IN;
        double acc = 0.0;
#pragma unroll 8
        for (int j = 0; j < 16; ++j) {
            int k = lane + j * 64;
            acc = fma((double)xr[k], (double)wc[k], acc);
        }
#pragma unroll 4
        for (int j = 0; j < 32; ++j) {
            int k = lane + j * 64;
            float zk = zr[k];
            if (zk != 0.f)
                acc = fma((double)zk, (double)wr[(size_t)k * UNITS + gcol], acc);
        }
#pragma unroll
        for (int off = 32; off >= 1; off >>= 1) acc += shflxor_d(acc, off);
        if (lane == 0) {
            size_t idx = (size_t)grow * UNITS + gcol;
            float zv = z[idx], bv = b[idx], vv = v[idx], rv = r[idx];
            float beta = (gcol < N_LIF) ? 0.f : BETA_C;
            float nb = DECAYB_C * bv + zv;
            float thr = THR_C + nb * beta;
            double nvd = (double)DECAY_C * (double)vv + acc - (double)zv * (double)THR_C;
            float nz = (rv > 0.f) ? 0.f : ((nvd - (double)thr > 0.0) ? 1.f : 0.f);
            float nr = fminf(fmaxf(rv + NREF_C * nz - 1.f, 0.f), NREF_C);
            oz[idx] = nz; ov[idx] = (float)nvd; orr[idx] = nr;
            int kp2 = gcol >> 6, c2 = (gcol & 63) >> 3, e2 = gcol & 7;
            nzbT[((size_t)(grow >> 7) * 32 + kp2) * 8192 + c2 * 1024 + (grow & 127) * 8 + e2]
                = (nz > 0.f) ? (unsigned short)0x3F80 : (unsigned short)0;
        }
    }
}

// ====== MFMA GEMM2 bf16, split-K-in-block (2 wave-groups x 16 steps) ======
__global__ __launch_bounds__(512)
void mfma_gemm2(const ushort_t* __restrict__ nzbT, const ushort_t* __restrict__ woHT,
                const float* __restrict__ prev, float* __restrict__ nout) {
    __shared__ ushort_t As[2][2][8192];     // [grp][buf]
    __shared__ ushort_t Bs[2][2][8192];
    const int t = threadIdx.x, lane = t & 63, w8 = t >> 6;
    const int grp = w8 >> 2, w = w8 & 3;
    const int wm = w >> 1, wn = w & 1;
    const int bid = blockIdx.x;
    const int swz = (bid & 7) * 32 + (bid >> 3);   // 256 blocks, bijective
    const int rby = swz >> 3, cbx = swz & 7;
    const int row0 = rby * 128, col0 = cbx * 128;
    const int l4 = lane >> 4, l15 = lane & 15;

    f32x4 acc[4][4];
#pragma unroll
    for (int m = 0; m < 4; ++m)
#pragma unroll
        for (int n = 0; n < 4; ++n)
#pragma unroll
            for (int i = 0; i < 4; ++i) acc[m][n][i] = 0.f;

    auto stage = [&](int sc, int buf) {
        const ushort_t* aB = nzbT + ((size_t)rby * 32 + sc) * 8192;
        const ushort_t* bB = woHT + ((size_t)cbx * 32 + sc) * 8192;
#pragma unroll
        for (int c = 0; c < 4; ++c) {
            int ch = w * 4 + c;
            gload_lds16(aB + ch * 512 + lane * 8, &As[grp][buf][ch * 512]);
            gload_lds16(bB + ch * 512 + lane * 8, &Bs[grp][buf][ch * 512]);
        }
    };

    stage(grp * 16, 0);
    __syncthreads();
    int cur = 0;
    for (int step = 0; step < 16; ++step) {
        if (step + 1 < 16) stage(grp * 16 + step + 1, cur ^ 1);
        const ushort_t* Ab = As[grp][cur];
        const ushort_t* Bb = Bs[grp][cur];
#pragma unroll
        for (int kk = 0; kk < 2; ++kk) {
            bf16x8 af[4], bfr[4];
            const int cBase = (kk * 4 + l4) * 1024;
#pragma unroll
            for (int m = 0; m < 4; ++m)
                af[m] = *reinterpret_cast<const bf16x8*>(Ab + cBase + (wm * 64 + m * 16 + l15) * 8);
#pragma unroll
            for (int n = 0; n < 4; ++n)
                bfr[n] = *reinterpret_cast<const bf16x8*>(Bb + cBase + (wn * 64 + n * 16 + l15) * 8);
#pragma unroll
            for (int m = 0; m < 4; ++m)
#pragma unroll
                for (int n = 0; n < 4; ++n)
                    acc[m][n] = __builtin_amdgcn_mfma_f32_16x16x32_bf16(
                        af[m], bfr[n], acc[m][n], 0, 0, 0);
        }
        __syncthreads();
        cur ^= 1;
    }

    // combine: group1 partials -> LDS (reuse As, 128*128 f32 = 64KB), group0 sums
    float* part = reinterpret_cast<float*>(As);
    if (grp == 1) {
#pragma unroll
        for (int m = 0; m < 4; ++m)
#pragma unroll
            for (int i = 0; i < 4; ++i) {
                int lr = wm * 64 + m * 16 + l4 * 4 + i;
#pragma unroll
                for (int n = 0; n < 4; ++n)
                    part[lr * 128 + wn * 64 + n * 16 + l15] = acc[m][n][i];
            }
    }
    __syncthreads();
    if (grp == 0) {
#pragma unroll
        for (int m = 0; m < 4; ++m)
#pragma unroll
            for (int i = 0; i < 4; ++i) {
                int lr = wm * 64 + m * 16 + l4 * 4 + i;
                size_t rbase = (size_t)(row0 + lr) * N_OUT;
#pragma unroll
                for (int n = 0; n < 4; ++n) {
                    int lc = wn * 64 + n * 16 + l15;
                    size_t idx = rbase + col0 + lc;
                    nout[idx] = KAPPA_C * prev[idx] + acc[m][n][i] + part[lr * 128 + lc];
                }
            }
    }
}

// ================= fp32 fallback (round-1 kernel; used if ws too small) =====
#define BM 128
#define BN 128
#define BK 16
#define TM 8
#define TN 8

__global__ __launch_bounds__(256)
void lsnn_gemm1(const float* __restrict__ x, const float* __restrict__ z,
                const float* __restrict__ w_in, const float* __restrict__ w_rec,
                const float* __restrict__ v, const float* __restrict__ r,
                const float* __restrict__ b,
                float* __restrict__ out_z, float* __restrict__ out_v,
                float* __restrict__ out_r, float* __restrict__ out_b) {
    __shared__ float As_[BK][BM + 4];
    __shared__ float Bs_[BK][BN + 4];
    const int bx = blockIdx.x, by = blockIdx.y, t = threadIdx.x;
    const int tx = t & 15, ty = t >> 4;
    const int row0 = by * BM, col0 = bx * BN;
    float acc[TM][TN];
#pragma unroll
    for (int i = 0; i < TM; ++i)
#pragma unroll
        for (int j = 0; j < TN; ++j) acc[i][j] = 0.f;
    for (int k0 = 0; k0 < N_IN + UNITS; k0 += BK) {
#pragma unroll
        for (int l = 0; l < 2; ++l) {
            int e = t + l * 256, arow = e >> 2, acol = (e & 3) * 4, gk = k0 + acol;
            const float* src = (gk < N_IN) ? (x + (size_t)(row0 + arow) * N_IN + gk)
                                           : (z + (size_t)(row0 + arow) * UNITS + (gk - N_IN));
            float4 av = *reinterpret_cast<const float4*>(src);
            As_[acol + 0][arow] = av.x; As_[acol + 1][arow] = av.y;
            As_[acol + 2][arow] = av.z; As_[acol + 3][arow] = av.w;
        }
#pragma unroll
        for (int l = 0; l < 2; ++l) {
            int e = t + l * 256, brow = e >> 5, bcol = (e & 31) * 4, gk = k0 + brow;
            const float* src = (gk < N_IN) ? (w_in + (size_t)gk * UNITS + col0 + bcol)
                                           : (w_rec + (size_t)(gk - N_IN) * UNITS + col0 + bcol);
            *reinterpret_cast<float4*>(&Bs_[brow][bcol]) = *reinterpret_cast<const float4*>(src);
        }
        __syncthreads();
#pragma unroll
        for (int kk = 0; kk < BK; ++kk) {
            float ra[TM], rb[TN];
#pragma unroll
            for (int i = 0; i < TM; ++i) ra[i] = As_[kk][ty * TM + i];
#pragma unroll
            for (int j = 0; j < TN; ++j) rb[j] = Bs_[kk][tx * TN + j];
#pragma unroll
            for (int i = 0; i < TM; ++i)
#pragma unroll
                for (int j = 0; j < TN; ++j) acc[i][j] = fmaf(ra[i], rb[j], acc[i][j]);
        }
        __syncthreads();
    }
#pragma unroll
    for (int i = 0; i < TM; ++i) {
        int gi = row0 + ty * TM + i;
        size_t base = (size_t)gi * UNITS;
#pragma unroll
        for (int j = 0; j < TN; ++j) {
            int gj = col0 + tx * TN + j;
            size_t idx = base + gj;
            float zv = z[idx], bv = b[idx], vv = v[idx], rv = r[idx];
            float beta = (gj < N_LIF) ? 0.f : BETA_C;
            float nb = DECAYB_C * bv + zv;
            float thr_ac = THR_C + nb * beta;
            float nv = DECAY_C * vv + acc[i][j] - zv * THR_C;
            float nz = (rv > 0.f) ? 0.f : (((nv - thr_ac) > 0.f) ? 1.f : 0.f);
            float nr = fminf(fmaxf(rv + NREF_C * nz - 1.f, 0.f), NREF_C);
            out_z[idx] = nz; out_v[idx] = nv; out_r[idx] = nr; out_b[idx] = nb;
        }
    }
}

__global__ __launch_bounds__(256)
void lsnn_gemm2(const float* __restrict__ nz, const float* __restrict__ w_out,
                const float* __restrict__ prev_out, float* __restrict__ new_out) {
    __shared__ float As_[BK][BM + 4];
    __shared__ float Bs_[BK][BN + 4];
    const int bx = blockIdx.x, by = blockIdx.y, t = threadIdx.x;
    const int tx = t & 15, ty = t >> 4;
    const int row0 = by * BM, col0 = bx * BN;
    float acc[TM][TN];
#pragma unroll
    for (int i = 0; i < TM; ++i)
#pragma unroll
        for (int j = 0; j < TN; ++j) acc[i][j] = 0.f;
    for (int k0 = 0; k0 < UNITS; k0 += BK) {
#pragma unroll
        for (int l = 0; l < 2; ++l) {
            int e = t + l * 256, arow = e >> 2, acol = (e & 3) * 4, gk = k0 + acol;
            float4 av = *reinterpret_cast<const float4*>(nz + (size_t)(row0 + arow) * UNITS + gk);
            As_[acol + 0][arow] = av.x; As_[acol + 1][arow] = av.y;
            As_[acol + 2][arow] = av.z; As_[acol + 3][arow] = av.w;
        }
#pragma unroll
        for (int l = 0; l < 2; ++l) {
            int e = t + l * 256, brow = e >> 5, bcol = (e & 31) * 4, gk = k0 + brow;
            *reinterpret_cast<float4*>(&Bs_[brow][bcol]) =
                *reinterpret_cast<const float4*>(w_out + (size_t)gk * N_OUT + col0 + bcol);
        }
        __syncthreads();
#pragma unroll
        for (int kk = 0; kk < BK; ++kk) {
            float ra[TM], rb[TN];
#pragma unroll
            for (int i = 0; i < TM; ++i) ra[i] = As_[kk][ty * TM + i];
#pragma unroll
            for (int j = 0; j < TN; ++j) rb[j] = Bs_[kk][tx * TN + j];
#pragma unroll
            for (int i = 0; i < TM; ++i)
#pragma unroll
                for (int j = 0; j < TN; ++j) acc[i][j] = fmaf(ra[i], rb[j], acc[i][j]);
        }
        __syncthreads();
    }
#pragma unroll
    for (int i = 0; i < TM; ++i) {
        int gi = row0 + ty * TM + i;
        size_t base = (size_t)gi * N_OUT;
#pragma unroll
        for (int j = 0; j < TN; ++j) {
            int gj = col0 + tx * TN + j;
            size_t idx = base + gj;
            new_out[idx] = KAPPA_C * prev_out[idx] + acc[i][j];
        }
    }
}

// ================= launch =================
extern "C" void kernel_launch(void* const* d_in, const int* in_sizes, int n_in,
                              void* d_out, int out_size, void* d_ws, size_t ws_size,
                              hipStream_t stream) {
    const float* x     = (const float*)d_in[0];
    const float* v     = (const float*)d_in[1];
    const float* z     = (const float*)d_in[2];
    const float* r     = (const float*)d_in[3];
    const float* out   = (const float*)d_in[4];
    const float* b     = (const float*)d_in[5];
    const float* w_in  = (const float*)d_in[6];
    const float* w_rec = (const float*)d_in[7];
    const float* w_out = (const float*)d_in[8];

    float* o       = (float*)d_out;
    float* new_out = o;
    float* new_z   = o + (size_t)B_SZ * N_OUT;
    float* new_v   = new_z + (size_t)B_SZ * UNITS;
    float* new_r   = new_v + (size_t)B_SZ * UNITS;
    float* new_b   = new_r + (size_t)B_SZ * UNITS;

    const size_t MB = 1u << 20;
    const size_t need = 66 * MB;
    if (ws_size >= need) {
        char* wsb = (char*)d_ws;
        ushort_t* xhT   = (ushort_t*)(wsb + 0 * MB);    // 8 MB  (fp16 x)
        ushort_t* zbT   = (ushort_t*)(wsb + 8 * MB);    // 16 MB (fp16 z, exact)
        ushort_t* nzbT  = (ushort_t*)(wsb + 24 * MB);   // 16 MB (bf16 new_z, tiled)
        ushort_t* wiT   = (ushort_t*)(wsb + 40 * MB);   // 4 MB  (fp16 w_in^T)
        ushort_t* wrT   = (ushort_t*)(wsb + 44 * MB);   // 8 MB  (fp16 w_rec^T)
        ushort_t* woHT  = (ushort_t*)(wsb + 52 * MB);   // 4 MB  (bf16 w_out^T)
        float*    wiT32 = (float*)   (wsb + 56 * MB);   // 8 MB  (fp32 w_in^T)
        unsigned* cnt   = (unsigned*)(wsb + 64 * MB);
        unsigned* list  = (unsigned*)(wsb + 64 * MB + 4096);  // 512 KB

        hipLaunchKernelGGL(prep_all, dim3(3072), dim3(256), 0, stream,
                           x, z, w_in, w_rec, w_out,
                           xhT, zbT, wiT, wrT, woHT, wiT32, cnt);
        hipLaunchKernelGGL(mfma_gemm1, dim3(512), dim3(256), 0, stream,
                           xhT, zbT, wiT, wrT,
                           z, v, r, b, new_z, new_v, new_r, new_b, nzbT, cnt, list);
        hipLaunchKernelGGL(fixup_kernel, dim3(NFIXWAVES / 4), dim3(256), 0, stream,
                           x, z, wiT32, w_rec, v, r, b, new_z, new_v, new_r, nzbT, cnt, list);
        hipLaunchKernelGGL(mfma_gemm2, dim3(256), dim3(512), 0, stream,
                           nzbT, woHT, out, new_out);
    } else {
        dim3 blk(256);
        hipLaunchKernelGGL(lsnn_gemm1, dim3(UNITS / BN, B_SZ / BM), blk, 0, stream,
                           x, z, w_in, w_rec, v, r, b, new_z, new_v, new_r, new_b);
        hipLaunchKernelGGL(lsnn_gemm2, dim3(N_OUT / BN, B_SZ / BM), blk, 0, stream,
                           new_z, w_out, out, new_out);
    }
}